// Round 14
// baseline (81.232 us; speedup 1.0000x reference)
//
#include <hip/hip_runtime.h>
#include <hip/hip_bf16.h>

#define ALPHA 0.2f
static __device__ __forceinline__ float lrel(float x) { return fmaxf(x, ALPHA * x); }

typedef __attribute__((ext_vector_type(8))) short bf16x8;
typedef __attribute__((ext_vector_type(16))) float f32x16;

union FragU { bf16x8 v; unsigned int u[4]; uint4 q; };

// pack two f32 -> one dword of 2 bf16 (RNE) via the HW instruction
static __device__ __forceinline__ unsigned int pk2(float a, float b) {
    unsigned int r;
    asm("v_cvt_pk_bf16_f32 %0, %1, %2" : "=v"(r) : "v"(a), "v"(b));
    return r;
}
// lrelu both, then pack to bf16 pair
static __device__ __forceinline__ unsigned int cvl2(float a, float b) {
    return pk2(lrel(a), lrel(b));
}
// f32 -> bf16 (RNE) scalar
static __device__ __forceinline__ unsigned short f2bf(float x) {
    union { float f; unsigned int u; } c;
    c.f = x;
    unsigned int r = c.u + 0x7FFFu + ((c.u >> 16) & 1u);
    return (unsigned short)(r >> 16);
}
// 32x32 D-slot <-> B-position K-gather: B-position k holds the h-value that
// GEMM-out D layout put at slot s(k). GEMM1/2 A-frags gather their K-dim by this.
static __device__ __forceinline__ int kslot(int k) {
    const int c = k >> 4, lh = (k >> 3) & 1, e = k & 7;
    const int rh = c >> 1, b = 2 * (c & 1) + ((e >> 2) & 1), a = e & 3;
    return 32 * rh + 8 * b + 4 * lh + a;
}

// ---------------- Kernel 1: U = x @ W0top + b0, x_bf, 32x32 weight fragments ----------------
// blocks 0..1023: U (unpermuted) + xbf. block 1024: pack W0bot/W1/W2 A-fragments
// for mfma_f32_32x32x16_bf16 (20 frags x 64 lanes x 4 dwords).
__global__ __launch_bounds__(256) void k_uv(
    const float* __restrict__ x, const float* __restrict__ W0, const float* __restrict__ b0,
    const float* __restrict__ W1, const float* __restrict__ W2,
    float* __restrict__ U, unsigned short* __restrict__ xbf, unsigned int* __restrict__ WF)
{
    if (blockIdx.x == 1024) {
        const int t = threadIdx.x;
        const int l = t & 63, part = t >> 6;
        const int lo32 = l & 31, lh = l >> 5;
        for (int f = part; f < 20; f += 4) {
            unsigned int o[4];
            if (f < 4) {
                // W0bot A-frag [rh][c]: A[row=32rh+lo32][k=16c+8lh+e] = W0[32+k][row]
                const int rh = f >> 1, c = f & 1;
#pragma unroll
                for (int q = 0; q < 4; ++q) {
                    const int k0 = 16 * c + 8 * lh + 2 * q;
                    o[q] = pk2(W0[(32 + k0) * 64 + 32 * rh + lo32],
                               W0[(33 + k0) * 64 + 32 * rh + lo32]);
                }
            } else if (f < 12) {
                // W1 A-frag [rh][c]: A[row][k] = W1[kslot(k)][row]
                const int idx = f - 4, rh = idx >> 2, c = idx & 3;
#pragma unroll
                for (int q = 0; q < 4; ++q) {
                    const int k0 = 16 * c + 8 * lh + 2 * q;
                    o[q] = pk2(W1[kslot(k0) * 64 + 32 * rh + lo32],
                               W1[kslot(k0 + 1) * 64 + 32 * rh + lo32]);
                }
            } else {
                // W2 A-frag [rh][c]: A[row][k] = W2[kslot(k)][row]
                const int idx = f - 12, rh = idx >> 2, c = idx & 3;
#pragma unroll
                for (int q = 0; q < 4; ++q) {
                    const int k0 = 16 * c + 8 * lh + 2 * q;
                    o[q] = pk2(W2[kslot(k0) * 64 + 32 * rh + lo32],
                               W2[kslot(k0 + 1) * 64 + 32 * rh + lo32]);
                }
            }
            *(uint4*)(WF + (f * 64 + l) * 4) = make_uint4(o[0], o[1], o[2], o[3]);
        }
        return;
    }
    const int idx = blockIdx.x * 256 + threadIdx.x;  // 0 .. 262143
    const int n = idx >> 6;
    const int kf = idx & 63;
    const float* xr = x + n * 32;
    float u = b0[kf];
#pragma unroll
    for (int i = 0; i < 32; ++i) u += xr[i] * W0[i * 64 + kf];
    U[idx] = u;
    if (kf < 32) xbf[n * 32 + kf] = f2bf(xr[kf]);
}

// D-layout gather for C-init / bias / U: slot r of tile rh, lane-half lh ->
// feature 32rh + (r&3) + 8*(r>>2) + 4lh. Loads as 4x float4 per tile.
#define LOAD_CINIT(dst, base)                                         \
    {                                                                 \
        _Pragma("unroll")                                             \
        for (int j = 0; j < 4; ++j) {                                 \
            const float4 t4 = *(const float4*)((base) + 4 * lh + 8 * j); \
            dst[4 * j + 0] = t4.x; dst[4 * j + 1] = t4.y;             \
            dst[4 * j + 2] = t4.z; dst[4 * j + 3] = t4.w;             \
        }                                                             \
    }

// ---------------- Kernel 2: edge MLP on 32x32x16 MFMAs + sum over j ----------------
// 32-edge tiles: GEMM0 (K=32, 4 MFMA) -> pairwise pack -> GEMM1 (K=64, 8 MFMA,
// A from LDS) -> pack -> GEMM2 (8 MFMA, A from LDS) -> fused lrel-agg.
// The kslot() prep-gather makes each GEMM's D registers pack pairwise-sequentially
// into the next GEMM's B-fragment. u/b1/b2 ride as MFMA C-init (D!=C).
// grid: 1024 blocks = 8(b) x 128(ig); 4 waves/block; 1 node per wave; 16 iters.
__global__ __launch_bounds__(256, 2) void k_edge(
    const float* __restrict__ U, const unsigned short* __restrict__ xbf,
    const unsigned int* __restrict__ WF,
    const float* __restrict__ b1, const float* __restrict__ b2,
    float* __restrict__ AGG)
{
    __shared__ uint4 wlds[1024];  // [0..7]=W1 frags (rh*4+c), [8..15]=W2 frags
    const int tid = threadIdx.x;
    const int w = tid >> 6, l = tid & 63;
    const int lo32 = l & 31, lh = l >> 5;
    const int bid = blockIdx.x;
    const int b = bid >> 7, ig = bid & 127;
    const int node = b * 512 + ig * 4 + w;

    // ---- stage W1/W2 fragments into LDS (once per block)
    for (int idx = tid; idx < 1024; idx += 256)
        wlds[idx] = ((const uint4*)WF)[256 + idx];

    // ---- W0bot fragments in registers (4 frags = 16 regs)
    FragU w0f[4];
    const uint4* wp = (const uint4*)WF;
#pragma unroll
    for (int f = 0; f < 4; ++f) w0f[f].q = wp[f * 64 + l];

    // ---- C-inits: u (per-node), b1, b2 in D-layout
    f32x16 u0fa, u0fb, b1fa, b1fb, b2fa, b2fb;
    LOAD_CINIT(u0fa, U + node * 64);
    LOAD_CINIT(u0fb, U + node * 64 + 32);
    LOAD_CINIT(b1fa, b1);
    LOAD_CINIT(b1fb, b1 + 32);
    LOAD_CINIT(b2fa, b2);
    LOAD_CINIT(b2fb, b2 + 32);

    const unsigned short* xb = xbf + b * 512 * 32;

    // ---- prefetch tile 0's xj B-frags (chunks c=0,1): B[k=16c+8lh+e][edge=lo32]
    FragU xj0, xj1;
    xj0.q = *(const uint4*)(xb + lo32 * 32 + 8 * lh);
    xj1.q = *(const uint4*)(xb + lo32 * 32 + 16 + 8 * lh);

    float agga[16], aggb[16];
#pragma unroll
    for (int r = 0; r < 16; ++r) { agga[r] = 0.f; aggb[r] = 0.f; }

    __syncthreads();

#pragma unroll 1
    for (int k = 0; k < 16; ++k) {
        // opaque zero: defeats LICM on the LDS weight reads
        int widx = 0;
        asm volatile("" : "+v"(widx));

        // prefetch next tile's xj
        const int jn = ((k + 1) & 15) * 32;
        FragU xjn0, xjn1;
        xjn0.q = *(const uint4*)(xb + (jn + lo32) * 32 + 8 * lh);
        xjn1.q = *(const uint4*)(xb + (jn + lo32) * 32 + 16 + 8 * lh);

        // ---- GEMM0: h0 = W0bot^T @ xj^T + u (C-init), K=32
        f32x16 acc0a = __builtin_amdgcn_mfma_f32_32x32x16_bf16(w0f[0].v, xj0.v, u0fa, 0, 0, 0);
        f32x16 acc0b = __builtin_amdgcn_mfma_f32_32x32x16_bf16(w0f[2].v, xj0.v, u0fb, 0, 0, 0);
        acc0a = __builtin_amdgcn_mfma_f32_32x32x16_bf16(w0f[1].v, xj1.v, acc0a, 0, 0, 0);
        acc0b = __builtin_amdgcn_mfma_f32_32x32x16_bf16(w0f[3].v, xj1.v, acc0b, 0, 0, 0);

        // ---- pack q (pairwise-sequential thanks to kslot gather)
        FragU q0, q1, q2, q3;
        q0.u[0] = cvl2(acc0a[0],  acc0a[1]);  q0.u[1] = cvl2(acc0a[2],  acc0a[3]);
        q0.u[2] = cvl2(acc0a[4],  acc0a[5]);  q0.u[3] = cvl2(acc0a[6],  acc0a[7]);
        q1.u[0] = cvl2(acc0a[8],  acc0a[9]);  q1.u[1] = cvl2(acc0a[10], acc0a[11]);
        q1.u[2] = cvl2(acc0a[12], acc0a[13]); q1.u[3] = cvl2(acc0a[14], acc0a[15]);
        q2.u[0] = cvl2(acc0b[0],  acc0b[1]);  q2.u[1] = cvl2(acc0b[2],  acc0b[3]);
        q2.u[2] = cvl2(acc0b[4],  acc0b[5]);  q2.u[3] = cvl2(acc0b[6],  acc0b[7]);
        q3.u[0] = cvl2(acc0b[8],  acc0b[9]);  q3.u[1] = cvl2(acc0b[10], acc0b[11]);
        q3.u[2] = cvl2(acc0b[12], acc0b[13]); q3.u[3] = cvl2(acc0b[14], acc0b[15]);

        // ---- GEMM1: K=64 (4 chunks), A from LDS, b1 C-init
        FragU wa, wb;
        wa.q = wlds[widx + 0 * 64 + l]; wb.q = wlds[widx + 4 * 64 + l];
        f32x16 acc1a = __builtin_amdgcn_mfma_f32_32x32x16_bf16(wa.v, q0.v, b1fa, 0, 0, 0);
        f32x16 acc1b = __builtin_amdgcn_mfma_f32_32x32x16_bf16(wb.v, q0.v, b1fb, 0, 0, 0);
        wa.q = wlds[widx + 1 * 64 + l]; wb.q = wlds[widx + 5 * 64 + l];
        acc1a = __builtin_amdgcn_mfma_f32_32x32x16_bf16(wa.v, q1.v, acc1a, 0, 0, 0);
        acc1b = __builtin_amdgcn_mfma_f32_32x32x16_bf16(wb.v, q1.v, acc1b, 0, 0, 0);
        wa.q = wlds[widx + 2 * 64 + l]; wb.q = wlds[widx + 6 * 64 + l];
        acc1a = __builtin_amdgcn_mfma_f32_32x32x16_bf16(wa.v, q2.v, acc1a, 0, 0, 0);
        acc1b = __builtin_amdgcn_mfma_f32_32x32x16_bf16(wb.v, q2.v, acc1b, 0, 0, 0);
        wa.q = wlds[widx + 3 * 64 + l]; wb.q = wlds[widx + 7 * 64 + l];
        acc1a = __builtin_amdgcn_mfma_f32_32x32x16_bf16(wa.v, q3.v, acc1a, 0, 0, 0);
        acc1b = __builtin_amdgcn_mfma_f32_32x32x16_bf16(wb.v, q3.v, acc1b, 0, 0, 0);

        // ---- pack p
        FragU p0, p1, p2, p3;
        p0.u[0] = cvl2(acc1a[0],  acc1a[1]);  p0.u[1] = cvl2(acc1a[2],  acc1a[3]);
        p0.u[2] = cvl2(acc1a[4],  acc1a[5]);  p0.u[3] = cvl2(acc1a[6],  acc1a[7]);
        p1.u[0] = cvl2(acc1a[8],  acc1a[9]);  p1.u[1] = cvl2(acc1a[10], acc1a[11]);
        p1.u[2] = cvl2(acc1a[12], acc1a[13]); p1.u[3] = cvl2(acc1a[14], acc1a[15]);
        p2.u[0] = cvl2(acc1b[0],  acc1b[1]);  p2.u[1] = cvl2(acc1b[2],  acc1b[3]);
        p2.u[2] = cvl2(acc1b[4],  acc1b[5]);  p2.u[3] = cvl2(acc1b[6],  acc1b[7]);
        p3.u[0] = cvl2(acc1b[8],  acc1b[9]);  p3.u[1] = cvl2(acc1b[10], acc1b[11]);
        p3.u[2] = cvl2(acc1b[12], acc1b[13]); p3.u[3] = cvl2(acc1b[14], acc1b[15]);

        // ---- GEMM2: K=64, A from LDS, b2 C-init
        wa.q = wlds[widx + 8 * 64 + l];  wb.q = wlds[widx + 12 * 64 + l];
        f32x16 acc2a = __builtin_amdgcn_mfma_f32_32x32x16_bf16(wa.v, p0.v, b2fa, 0, 0, 0);
        f32x16 acc2b = __builtin_amdgcn_mfma_f32_32x32x16_bf16(wb.v, p0.v, b2fb, 0, 0, 0);
        wa.q = wlds[widx + 9 * 64 + l];  wb.q = wlds[widx + 13 * 64 + l];
        acc2a = __builtin_amdgcn_mfma_f32_32x32x16_bf16(wa.v, p1.v, acc2a, 0, 0, 0);
        acc2b = __builtin_amdgcn_mfma_f32_32x32x16_bf16(wb.v, p1.v, acc2b, 0, 0, 0);
        wa.q = wlds[widx + 10 * 64 + l]; wb.q = wlds[widx + 14 * 64 + l];
        acc2a = __builtin_amdgcn_mfma_f32_32x32x16_bf16(wa.v, p2.v, acc2a, 0, 0, 0);
        acc2b = __builtin_amdgcn_mfma_f32_32x32x16_bf16(wb.v, p2.v, acc2b, 0, 0, 0);
        wa.q = wlds[widx + 11 * 64 + l]; wb.q = wlds[widx + 15 * 64 + l];
        acc2a = __builtin_amdgcn_mfma_f32_32x32x16_bf16(wa.v, p3.v, acc2a, 0, 0, 0);
        acc2b = __builtin_amdgcn_mfma_f32_32x32x16_bf16(wb.v, p3.v, acc2b, 0, 0, 0);

        // ---- fused lrel-agg: agg += 0.6x + 0.4|x|  (== agg += lrel(x))
#pragma unroll
        for (int r = 0; r < 16; ++r) {
            agga[r] = fmaf(0.6f, acc2a[r], fmaf(0.4f, fabsf(acc2a[r]), agga[r]));
            aggb[r] = fmaf(0.6f, acc2b[r], fmaf(0.4f, fabsf(acc2b[r]), aggb[r]));
        }

        xj0 = xjn0; xj1 = xjn1;
    }

    // ---- reduce over the 32 edge-lanes (lo32); lanes lo32==0 hold full sums
#pragma unroll
    for (int r = 0; r < 16; ++r) {
        float va = agga[r], vb = aggb[r];
        va += __shfl_xor(va, 1);  vb += __shfl_xor(vb, 1);
        va += __shfl_xor(va, 2);  vb += __shfl_xor(vb, 2);
        va += __shfl_xor(va, 4);  vb += __shfl_xor(vb, 4);
        va += __shfl_xor(va, 8);  vb += __shfl_xor(vb, 8);
        va += __shfl_xor(va, 16); vb += __shfl_xor(vb, 16);
        agga[r] = va; aggb[r] = vb;
    }
    if (lo32 == 0) {
#pragma unroll
        for (int j = 0; j < 4; ++j) {
            float4 oa = {agga[4 * j], agga[4 * j + 1], agga[4 * j + 2], agga[4 * j + 3]};
            *(float4*)(AGG + node * 64 + 4 * lh + 8 * j) = oa;
            float4 ob = {aggb[4 * j], aggb[4 * j + 1], aggb[4 * j + 2], aggb[4 * j + 3]};
            *(float4*)(AGG + node * 64 + 32 + 4 * lh + 8 * j) = ob;
        }
    }
}

// ---------------- Kernel 3: node MLP fn: [agg, x] -> 128 -> 128 -> 32 ----------------
__global__ __launch_bounds__(256) void k_fn(
    const float* __restrict__ AGG, const float* __restrict__ x,
    const float* __restrict__ W0, const float* __restrict__ b0,
    const float* __restrict__ W1, const float* __restrict__ b1,
    const float* __restrict__ W2, const float* __restrict__ b2,
    float* __restrict__ out)
{
    __shared__ float in96T[96][8];
    __shared__ float h1T[128][8];
    __shared__ float h2T[128][8];
    const int t = threadIdx.x;
    const int half = t >> 7, f = t & 127;
    const int node0 = blockIdx.x * 8;

    for (int idx = t; idx < 768; idx += 256) {
        int nn = idx & 7, k = idx >> 3;
        in96T[k][nn] = (k < 64) ? AGG[(node0 + nn) * 64 + k]
                                : x[(node0 + nn) * 32 + (k - 64)];
    }
    __syncthreads();

    {
        float a0 = b0[f], a1 = a0, a2 = a0, a3 = a0;
#pragma unroll 4
        for (int k = 0; k < 96; ++k) {
            const float4 iv = *(const float4*)(&in96T[k][4 * half]);
            const float wv = W0[k * 128 + f];
            a0 += iv.x * wv; a1 += iv.y * wv; a2 += iv.z * wv; a3 += iv.w * wv;
        }
        float4 o = {lrel(a0), lrel(a1), lrel(a2), lrel(a3)};
        *(float4*)(&h1T[f][4 * half]) = o;
    }
    __syncthreads();

    {
        float a0 = b1[f], a1 = a0, a2 = a0, a3 = a0;
#pragma unroll 4
        for (int k = 0; k < 128; ++k) {
            const float4 iv = *(const float4*)(&h1T[k][4 * half]);
            const float wv = W1[k * 128 + f];
            a0 += iv.x * wv; a1 += iv.y * wv; a2 += iv.z * wv; a3 += iv.w * wv;
        }
        float4 o = {lrel(a0), lrel(a1), lrel(a2), lrel(a3)};
        *(float4*)(&h2T[f][4 * half]) = o;
    }
    __syncthreads();

    {
        const int nn = t >> 5, fo = t & 31;
        float a = b2[fo];
#pragma unroll 4
        for (int k = 0; k < 128; ++k) a += h2T[k][nn] * W2[k * 32 + fo];
        out[(node0 + nn) * 32 + fo] = a;
    }
}

extern "C" void kernel_launch(void* const* d_in, const int* in_sizes, int n_in,
                              void* d_out, int out_size, void* d_ws, size_t ws_size,
                              hipStream_t stream)
{
    const float* x    = (const float*)d_in[0];
    const float* feW0 = (const float*)d_in[1];
    const float* feb0 = (const float*)d_in[2];
    const float* feW1 = (const float*)d_in[3];
    const float* feb1 = (const float*)d_in[4];
    const float* feW2 = (const float*)d_in[5];
    const float* feb2 = (const float*)d_in[6];
    const float* fnW0 = (const float*)d_in[7];
    const float* fnb0 = (const float*)d_in[8];
    const float* fnW1 = (const float*)d_in[9];
    const float* fnb1 = (const float*)d_in[10];
    const float* fnW2 = (const float*)d_in[11];
    const float* fnb2 = (const float*)d_in[12];
    float* out = (float*)d_out;

    // workspace: U (1MB) | AGG (1MB) | xbf (256KB) | WF (20KB)
    float* U   = (float*)d_ws;
    float* AGG = U + 262144;
    unsigned short* xbf = (unsigned short*)(AGG + 262144);
    unsigned int* WF = (unsigned int*)(xbf + 131072);

    hipLaunchKernelGGL(k_uv,   dim3(1025), dim3(256), 0, stream, x, feW0, feb0, feW1, feW2, U, xbf, WF);
    hipLaunchKernelGGL(k_edge, dim3(1024), dim3(256), 0, stream, U, xbf, WF, feb1, feb2, AGG);
    hipLaunchKernelGGL(k_fn,   dim3(512),  dim3(256), 0, stream, AGG, x, fnW0, fnb0, fnW1, fnb1, fnW2, fnb2, out);
}

// Round 15
// 73.563 us; speedup vs baseline: 1.1042x; 1.1042x over previous
//
#include <hip/hip_runtime.h>
#include <hip/hip_bf16.h>

#define ALPHA 0.2f
static __device__ __forceinline__ float lrel(float x) { return fmaxf(x, ALPHA * x); }

typedef __attribute__((ext_vector_type(8))) short bf16x8;
typedef __attribute__((ext_vector_type(4))) float f32x4;

union FragU { bf16x8 v; unsigned int u[4]; uint4 q; };

// VGPR-form MFMA via inline asm: "v" constraints pin A/B/C/D to arch VGPRs,
// eliminating the compiler's AGPR round-trips (v_accvgpr_read/write) on every
// accumulator touch. "=&v" earlyclobber keeps D disjoint from A/B/C.
static __device__ __forceinline__ f32x4 mfma_init(bf16x8 a, bf16x8 b, f32x4 c) {
    f32x4 d;
    asm("v_mfma_f32_16x16x32_bf16 %0, %1, %2, %3" : "=&v"(d) : "v"(a), "v"(b), "v"(c));
    return d;
}
static __device__ __forceinline__ void mfma_acc(f32x4& acc, bf16x8 a, bf16x8 b) {
    asm("v_mfma_f32_16x16x32_bf16 %0, %1, %2, %0" : "+v"(acc) : "v"(a), "v"(b));
}

// pack two f32 -> one dword of 2 bf16 (RNE) via the HW instruction
static __device__ __forceinline__ unsigned int pk2(float a, float b) {
    unsigned int r;
    asm("v_cvt_pk_bf16_f32 %0, %1, %2" : "=v"(r) : "v"(a), "v"(b));
    return r;
}
// lrelu both, then pack to bf16 pair
static __device__ __forceinline__ unsigned int cvl2(float a, float b) {
    return pk2(lrel(a), lrel(b));
}
// a += |x|  (VOP3 abs input modifier: single v_add)
static __device__ __forceinline__ void addabs(float& a, float x) {
    asm("v_add_f32 %0, %0, |%1|" : "+v"(a) : "v"(x));
}
// f32 -> bf16 (RNE) scalar
static __device__ __forceinline__ unsigned short f2bf(float x) {
    union { float f; unsigned int u; } c;
    c.f = x;
    unsigned int r = c.u + 0x7FFFu + ((c.u >> 16) & 1u);
    return (unsigned short)(r >> 16);
}
// pi permutation on 64 features: slot(16nf+4a+r) -> 32(nf>>1)+8a+4(nf&1)+r
static __device__ __forceinline__ int pi64(int s) {
    return 32 * ((s >> 4) >> 1) + 8 * ((s >> 2) & 3) + 4 * ((s >> 4) & 1) + (s & 3);
}

// ---------------- Kernel 1: Upi = pi(x @ W0top + b0), x_bf, weight fragments ----------------
__global__ __launch_bounds__(256) void k_uv(
    const float* __restrict__ x, const float* __restrict__ W0, const float* __restrict__ b0,
    const float* __restrict__ W1, const float* __restrict__ W2,
    float* __restrict__ Upi, unsigned short* __restrict__ xbf, unsigned int* __restrict__ WF)
{
    if (blockIdx.x == 1024) {
        const int t = threadIdx.x;
        const int l = t & 63, part = t >> 6;
        const int lo = l & 15, g = l >> 4;
        for (int ff = part; ff < 20; ff += 4) {
            unsigned int o[4];
            if (ff < 4) {
                const int nf = ff;
                const int pc = 32 * (nf >> 1) + 8 * (lo >> 2) + 4 * (nf & 1) + (lo & 3);
#pragma unroll
                for (int uq = 0; uq < 4; ++uq) {
                    const int k0 = 8 * g + 2 * uq;
                    o[uq] = pk2(W0[(32 + k0) * 64 + pc], W0[(33 + k0) * 64 + pc]);
                }
            } else if (ff < 12) {
                const int s = (ff - 4) >> 2, nf = (ff - 4) & 3;
                const int pc = 32 * (nf >> 1) + 8 * (lo >> 2) + 4 * (nf & 1) + (lo & 3);
#pragma unroll
                for (int uq = 0; uq < 4; ++uq) {
                    const int k0 = 32 * s + 8 * g + 2 * uq;
                    o[uq] = pk2(W1[k0 * 64 + pc], W1[(k0 + 1) * 64 + pc]);
                }
            } else {
                const int s = (ff - 12) >> 2, nf = (ff - 12) & 3;
                const int c2 = 16 * nf + lo;
#pragma unroll
                for (int uq = 0; uq < 4; ++uq) {
                    const int k0 = 32 * s + 8 * g + 2 * uq;
                    o[uq] = pk2(W2[k0 * 64 + c2], W2[(k0 + 1) * 64 + c2]);
                }
            }
            *(uint4*)(WF + (ff * 64 + l) * 4) = make_uint4(o[0], o[1], o[2], o[3]);
        }
        return;
    }
    const int idx = blockIdx.x * 256 + threadIdx.x;
    const int n = idx >> 6;
    const int slot = idx & 63;
    const int f = pi64(slot);
    const float* xr = x + n * 32;
    float u = b0[f];
#pragma unroll
    for (int i = 0; i < 32; ++i) u += xr[i] * W0[i * 64 + f];
    Upi[idx] = u;
    if (slot < 32) xbf[n * 32 + slot] = f2bf(xr[slot]);
}

// ---------------- Kernel 2: edge MLP (all 3 layers on MFMA) + sum over j ----------------
// R11 structure (skewed pipeline, W1 from LDS, W0/W2 in regs) with ALL MFMAs in
// VGPR-form via inline asm: no AGPR accumulator round-trips.
__global__ __launch_bounds__(256, 2) void k_edge(
    const float* __restrict__ Upi, const unsigned short* __restrict__ xbf,
    const unsigned int* __restrict__ WF,
    const float* __restrict__ b1, const float* __restrict__ b2,
    float* __restrict__ AGG)
{
    __shared__ uint4 wlds[512];  // w1f frags only: [0..7] = (s*4+nf)
    const int tid = threadIdx.x;
    const int w = tid >> 6, l = tid & 63;
    const int lo = l & 15, g = l >> 4;
    const int bid = blockIdx.x;
    const int b = bid >> 7, ig = bid & 127;
    const int node = b * 512 + ig * 4 + w;

    // ---- stage W1 fragments into LDS (once per block)
    for (int idx = tid; idx < 512; idx += 256)
        wlds[idx] = ((const uint4*)WF)[256 + idx];

    // ---- W0bot + W2 fragments in registers
    FragU w0f[4], w2f[2][4];
    const uint4* wp = (const uint4*)WF;
#pragma unroll
    for (int nf = 0; nf < 4; ++nf) w0f[nf].q = wp[nf * 64 + l];
#pragma unroll
    for (int s = 0; s < 2; ++s)
#pragma unroll
        for (int nf = 0; nf < 4; ++nf) w2f[s][nf].q = wp[(12 + s * 4 + nf) * 64 + l];

    // ---- per-i C-init for GEMM0 (Upi broadcast) + bias C-inits
    f32x4 u0f[4], b1f[4], b2f[4];
#pragma unroll
    for (int nf = 0; nf < 4; ++nf) {
        const float4 t0 = *(const float4*)(Upi + node * 64 + nf * 16 + 4 * g);
        u0f[nf] = (f32x4){t0.x, t0.y, t0.z, t0.w};
        const float4 t1 = *(const float4*)(b1 + 32 * (nf >> 1) + 8 * g + 4 * (nf & 1));
        const float4 t2 = *(const float4*)(b2 + 16 * nf + 4 * g);
        b1f[nf] = (f32x4){t1.x, t1.y, t1.z, t1.w};
        b2f[nf] = (f32x4){t2.x, t2.y, t2.z, t2.w};
    }

    const unsigned short* xb = xbf + b * 512 * 32;

    // ---- prologue: xj frags for tiles 0,1; GEMM0 for tile 0
    FragU xjT0, xjB;
    xjT0.q = *(const uint4*)(xb + lo * 32 + 8 * g);         // tile 0
    xjB.q  = *(const uint4*)(xb + (16 + lo) * 32 + 8 * g);  // tile 1

    __syncthreads();

    f32x4 acc0c[4];
#pragma unroll
    for (int nf = 0; nf < 4; ++nf)
        acc0c[nf] = mfma_init(w0f[nf].v, xjT0.v, u0f[nf]);

    f32x4 acc2p[4];
#pragma unroll
    for (int nf = 0; nf < 4; ++nf) { f32x4 z = {0.f, 0.f, 0.f, 0.f}; acc2p[nf] = z; }

    float aggL[4][4], aggA[4][4];
#pragma unroll
    for (int nf = 0; nf < 4; ++nf)
#pragma unroll
        for (int r = 0; r < 4; ++r) { aggL[nf][r] = 0.f; aggA[nf][r] = 0.f; }

#pragma unroll 2
    for (int k = 0; k < 32; ++k) {
        // opaque zero: defeats LICM on the LDS weight reads
        int widx = 0;
        asm volatile("" : "+v"(widx));

        // load xj for tile k+2 (wraps; garbage tile never aggregated)
        const int jn = ((k + 2) & 31) * 16;
        FragU xjn;
        xjn.q = *(const uint4*)(xb + (jn + lo) * 32 + 8 * g);

        // ---- GEMM0 for tile k+1 (skewed one tile ahead)
        __builtin_amdgcn_s_setprio(1);
        f32x4 acc0n[4];
#pragma unroll
        for (int nf = 0; nf < 4; ++nf)
            acc0n[nf] = mfma_init(w0f[nf].v, xjB.v, u0f[nf]);
        __builtin_amdgcn_s_setprio(0);

        // ---- pack q from tile k's acc0 (overlaps GEMM0 MFMAs)
        FragU q0, q1;
        q0.u[0] = cvl2(acc0c[0][0], acc0c[0][1]);
        q0.u[1] = cvl2(acc0c[0][2], acc0c[0][3]);
        q0.u[2] = cvl2(acc0c[1][0], acc0c[1][1]);
        q0.u[3] = cvl2(acc0c[1][2], acc0c[1][3]);
        q1.u[0] = cvl2(acc0c[2][0], acc0c[2][1]);
        q1.u[1] = cvl2(acc0c[2][2], acc0c[2][3]);
        q1.u[2] = cvl2(acc0c[3][0], acc0c[3][1]);
        q1.u[3] = cvl2(acc0c[3][2], acc0c[3][3]);

        // ---- GEMM1 (W1 from LDS, bias C-init)
        __builtin_amdgcn_s_setprio(1);
        f32x4 acc1[4];
#pragma unroll
        for (int nf = 0; nf < 4; ++nf) {
            FragU wa, wb;
            wa.q = wlds[widx + nf * 64 + l];
            wb.q = wlds[widx + (4 + nf) * 64 + l];
            acc1[nf] = mfma_init(wa.v, q0.v, b1f[nf]);
            mfma_acc(acc1[nf], wb.v, q1.v);
        }
        __builtin_amdgcn_s_setprio(0);

        // ---- agg of PREVIOUS tile's acc2 (overlaps GEMM1 MFMAs)
#pragma unroll
        for (int nf = 0; nf < 4; ++nf)
#pragma unroll
            for (int r = 0; r < 4; ++r) {
                aggL[nf][r] += acc2p[nf][r];
                addabs(aggA[nf][r], acc2p[nf][r]);
            }

        // ---- pack p from acc1 (pi trick: regs are GEMM2's B-fragment)
        FragU p0, p1;
        p0.u[0] = cvl2(acc1[0][0], acc1[0][1]);
        p0.u[1] = cvl2(acc1[0][2], acc1[0][3]);
        p0.u[2] = cvl2(acc1[1][0], acc1[1][1]);
        p0.u[3] = cvl2(acc1[1][2], acc1[1][3]);
        p1.u[0] = cvl2(acc1[2][0], acc1[2][1]);
        p1.u[1] = cvl2(acc1[2][2], acc1[2][3]);
        p1.u[2] = cvl2(acc1[3][0], acc1[3][1]);
        p1.u[3] = cvl2(acc1[3][2], acc1[3][3]);

        // ---- GEMM2 (W2 in regs, bias C-init) -> becomes "previous" for next iter
        __builtin_amdgcn_s_setprio(1);
#pragma unroll
        for (int nf = 0; nf < 4; ++nf) {
            acc2p[nf] = mfma_init(w2f[0][nf].v, p0.v, b2f[nf]);
            mfma_acc(acc2p[nf], w2f[1][nf].v, p1.v);
        }
        __builtin_amdgcn_s_setprio(0);

        // ---- rotate skew buffers (unroll-2 ping-pongs, no copies)
#pragma unroll
        for (int nf = 0; nf < 4; ++nf) acc0c[nf] = acc0n[nf];
        xjB = xjn;
    }

    // ---- epilogue: agg the last tile's acc2
#pragma unroll
    for (int nf = 0; nf < 4; ++nf)
#pragma unroll
        for (int r = 0; r < 4; ++r) {
            aggL[nf][r] += acc2p[nf][r];
            addabs(aggA[nf][r], acc2p[nf][r]);
        }

    // ---- combine lrel parts, reduce over the 16 edge-lanes, store
#pragma unroll
    for (int nf = 0; nf < 4; ++nf)
#pragma unroll
        for (int r = 0; r < 4; ++r) {
            float v = 0.6f * aggL[nf][r] + 0.4f * aggA[nf][r];
            v += __shfl_xor(v, 1);
            v += __shfl_xor(v, 2);
            v += __shfl_xor(v, 4);
            v += __shfl_xor(v, 8);
            aggL[nf][r] = v;
        }
    if (lo == 0) {
#pragma unroll
        for (int nf = 0; nf < 4; ++nf) {
            float4 o = {aggL[nf][0], aggL[nf][1], aggL[nf][2], aggL[nf][3]};
            *(float4*)(AGG + node * 64 + 16 * nf + 4 * g) = o;
        }
    }
}

// ---------------- Kernel 3: node MLP fn: [agg, x] -> 128 -> 128 -> 32 ----------------
__global__ __launch_bounds__(256) void k_fn(
    const float* __restrict__ AGG, const float* __restrict__ x,
    const float* __restrict__ W0, const float* __restrict__ b0,
    const float* __restrict__ W1, const float* __restrict__ b1,
    const float* __restrict__ W2, const float* __restrict__ b2,
    float* __restrict__ out)
{
    __shared__ float in96T[96][8];
    __shared__ float h1T[128][8];
    __shared__ float h2T[128][8];
    const int t = threadIdx.x;
    const int half = t >> 7, f = t & 127;
    const int node0 = blockIdx.x * 8;

    for (int idx = t; idx < 768; idx += 256) {
        int nn = idx & 7, k = idx >> 3;
        in96T[k][nn] = (k < 64) ? AGG[(node0 + nn) * 64 + k]
                                : x[(node0 + nn) * 32 + (k - 64)];
    }
    __syncthreads();

    {
        float a0 = b0[f], a1 = a0, a2 = a0, a3 = a0;
#pragma unroll 4
        for (int k = 0; k < 96; ++k) {
            const float4 iv = *(const float4*)(&in96T[k][4 * half]);
            const float wv = W0[k * 128 + f];
            a0 += iv.x * wv; a1 += iv.y * wv; a2 += iv.z * wv; a3 += iv.w * wv;
        }
        float4 o = {lrel(a0), lrel(a1), lrel(a2), lrel(a3)};
        *(float4*)(&h1T[f][4 * half]) = o;
    }
    __syncthreads();

    {
        float a0 = b1[f], a1 = a0, a2 = a0, a3 = a0;
#pragma unroll 4
        for (int k = 0; k < 128; ++k) {
            const float4 iv = *(const float4*)(&h1T[k][4 * half]);
            const float wv = W1[k * 128 + f];
            a0 += iv.x * wv; a1 += iv.y * wv; a2 += iv.z * wv; a3 += iv.w * wv;
        }
        float4 o = {lrel(a0), lrel(a1), lrel(a2), lrel(a3)};
        *(float4*)(&h2T[f][4 * half]) = o;
    }
    __syncthreads();

    {
        const int nn = t >> 5, fo = t & 31;
        float a = b2[fo];
#pragma unroll 4
        for (int k = 0; k < 128; ++k) a += h2T[k][nn] * W2[k * 32 + fo];
        out[(node0 + nn) * 32 + fo] = a;
    }
}

extern "C" void kernel_launch(void* const* d_in, const int* in_sizes, int n_in,
                              void* d_out, int out_size, void* d_ws, size_t ws_size,
                              hipStream_t stream)
{
    const float* x    = (const float*)d_in[0];
    const float* feW0 = (const float*)d_in[1];
    const float* feb0 = (const float*)d_in[2];
    const float* feW1 = (const float*)d_in[3];
    const float* feb1 = (const float*)d_in[4];
    const float* feW2 = (const float*)d_in[5];
    const float* feb2 = (const float*)d_in[6];
    const float* fnW0 = (const float*)d_in[7];
    const float* fnb0 = (const float*)d_in[8];
    const float* fnW1 = (const float*)d_in[9];
    const float* fnb1 = (const float*)d_in[10];
    const float* fnW2 = (const float*)d_in[11];
    const float* fnb2 = (const float*)d_in[12];
    float* out = (float*)d_out;

    // workspace: Upi (1MB) | AGG (1MB) | xbf (256KB) | WF (20KB)
    float* Upi = (float*)d_ws;
    float* AGG = Upi + 262144;
    unsigned short* xbf = (unsigned short*)(AGG + 262144);
    unsigned int* WF = (unsigned int*)(xbf + 131072);

    hipLaunchKernelGGL(k_uv,   dim3(1025), dim3(256), 0, stream, x, feW0, feb0, feW1, feW2, Upi, xbf, WF);
    hipLaunchKernelGGL(k_edge, dim3(1024), dim3(256), 0, stream, Upi, xbf, WF, feb1, feb2, AGG);
    hipLaunchKernelGGL(k_fn,   dim3(512),  dim3(256), 0, stream, AGG, x, fnW0, fnb0, fnW1, fnb1, fnW2, fnb2, out);
}